// Round 1
// baseline (1433.879 us; speedup 1.0000x reference)
//
#include <hip/hip_runtime.h>
#include <hip/hip_bf16.h>

// SlotMemoryCompressor on MI355X (gfx950).
// Pipeline (all bf16 MFMA for the 4 heavy GEMMs, f32 elsewhere):
//  Wt transposes -> Xbf16 -> q(SIMT) -> proj GEMM (K|V|RQ) -> L1 logits ->
//  softmax_T -> V^T -> attn@V (splitK atomic) -> @Wo -> LN(slots)+out ->
//  rk/rv GEMM (splitK) -> rv^T -> L2 logits -> softmax_S -> rmid GEMM ->
//  rmid@Wro (bf16, aliased on Xb) -> fused LN+gate+MSE loss -> finalize.

#define DEVI __device__ __forceinline__

typedef __attribute__((ext_vector_type(4))) float f32x4;
typedef __attribute__((ext_vector_type(8))) __bf16 bf16x8;

DEVI float bf2f(unsigned short u) {
    unsigned int x = ((unsigned int)u) << 16;
    return __uint_as_float(x);
}
DEVI unsigned short f2bf(float f) {  // RNE
    unsigned int u = __float_as_uint(f);
    unsigned int r = (u + 0x7FFFu + ((u >> 16) & 1u)) >> 16;
    return (unsigned short)r;
}

DEVI void gl_lds16(const void* g, void* l) {
    __builtin_amdgcn_global_load_lds(
        (const __attribute__((address_space(1))) void*)g,
        (__attribute__((address_space(3))) void*)l, 16, 0, 0);
}

// ---------------- elementwise convert f32 -> bf16 (vector x4) ----------------
__global__ __launch_bounds__(256) void k_cvt_bf16(const float* __restrict__ in,
                                                  unsigned short* __restrict__ out,
                                                  long n) {
    long i = ((long)blockIdx.x * blockDim.x + threadIdx.x) * 4;
    long stride = (long)gridDim.x * blockDim.x * 4;
    for (long j = i; j < n; j += stride) {
        float4 v = *(const float4*)(in + j);
        ushort4 o;
        o.x = f2bf(v.x); o.y = f2bf(v.y); o.z = f2bf(v.z); o.w = f2bf(v.w);
        *(ushort4*)(out + j) = o;
    }
}

// ---------------- transpose f32[R][C] -> bf16[C][R] ----------------
__global__ __launch_bounds__(256) void k_transpose_f2b(const float* __restrict__ in, int ldin, long long sIn,
                                                       unsigned short* __restrict__ out, int ldout, long long sOut) {
    __shared__ float tile[32][33];
    in += (long long)blockIdx.z * sIn;
    out += (long long)blockIdx.z * sOut;
    int c0 = blockIdx.x * 32, r0 = blockIdx.y * 32;
    int tx = threadIdx.x, ty = threadIdx.y;  // (32,8)
#pragma unroll
    for (int i = 0; i < 4; i++)
        tile[ty + i * 8][tx] = in[(size_t)(r0 + ty + i * 8) * ldin + c0 + tx];
    __syncthreads();
#pragma unroll
    for (int i = 0; i < 4; i++)
        out[(size_t)(c0 + ty + i * 8) * ldout + r0 + tx] = f2bf(tile[tx][ty + i * 8]);
}

// ---------------- transpose bf16[R][C] -> bf16[C][R] ----------------
__global__ __launch_bounds__(256) void k_transpose_b2b(const unsigned short* __restrict__ in, int ldin, long long sIn,
                                                       unsigned short* __restrict__ out, int ldout, long long sOut) {
    __shared__ unsigned short tile[32][33];
    in += (long long)blockIdx.z * sIn;
    out += (long long)blockIdx.z * sOut;
    int c0 = blockIdx.x * 32, r0 = blockIdx.y * 32;
    int tx = threadIdx.x, ty = threadIdx.y;
#pragma unroll
    for (int i = 0; i < 4; i++)
        tile[ty + i * 8][tx] = in[(size_t)(r0 + ty + i * 8) * ldin + c0 + tx];
    __syncthreads();
#pragma unroll
    for (int i = 0; i < 4; i++)
        out[(size_t)(c0 + ty + i * 8) * ldout + r0 + tx] = tile[tx][ty + i * 8];
}

// ---------------- q = slot_emb @ Wq (f32 SIMT, 64 rows) ----------------
__global__ __launch_bounds__(256) void k_q(const float* __restrict__ slot_emb,
                                           const float* __restrict__ Wq,
                                           unsigned short* __restrict__ q_b) {
    __shared__ float sl[4096];
    int s = blockIdx.x;
    for (int k = threadIdx.x; k < 4096; k += 256) sl[k] = slot_emb[(size_t)s * 4096 + k];
    __syncthreads();
    float acc = 0.f;
    int n = threadIdx.x;
#pragma unroll 4
    for (int k = 0; k < 4096; k++) acc = fmaf(sl[k], Wq[(size_t)k * 256 + n], acc);
    q_b[s * 256 + n] = f2bf(acc);
}

// ---------------- templated MFMA GEMM: C = alpha * A[M,K] @ Bt[N,K]^T ----------------
// A,Bt bf16 row-major (lda/ldb in elements, batch strides), BK=64, 4 waves.
// OMODE: 0 = f32 store, 1 = bf16 store, 2 = f32 atomicAdd (split-K partials).
template <int BM, int BN, int WR, int WC, int OMODE>
__global__ __launch_bounds__(256) void k_gemm(const unsigned short* __restrict__ A, int lda, long long sA,
                                              const unsigned short* __restrict__ B, int ldb, long long sB,
                                              void* __restrict__ Cv, int ldc, long long sC,
                                              int K, int ksplit, float alpha) {
    constexpr int NW = WR * WC;
    static_assert(NW == 4, "4 waves");
    __shared__ alignas(1024) unsigned short As[BM * 64];
    __shared__ alignas(1024) unsigned short Bs[BN * 64];
    const int tid = threadIdx.x;
    const int lane = tid & 63;
    const int wv = tid >> 6;
    const int batch = blockIdx.z / ksplit;
    const int ks = blockIdx.z - batch * ksplit;
    const unsigned short* Ab = A + (long long)batch * sA;
    const unsigned short* Bb = B + (long long)batch * sB;
    const int bm0 = blockIdx.x * BM;
    const int bn0 = blockIdx.y * BN;
    const int kchunk = K / ksplit;
    const int kt0 = (ks * kchunk) >> 6;
    const int kt1 = ((ks + 1) * kchunk) >> 6;

    constexpr int WTM = BM / WR, WTN = BN / WC;
    constexpr int FM = WTM / 16, FN = WTN / 16;
    const int wr = wv / WC, wc = wv % WC;

    f32x4 acc[FM][FN] = {};

    constexpr int CA = BM / 8, CB = BN / 8;
    constexpr int PW = (CA + CB) / NW;

    for (int kt = kt0; kt < kt1; ++kt) {
        const int k0 = kt << 6;
#pragma unroll
        for (int i = 0; i < PW; i++) {
            int c = wv * PW + i;
            if (c < CA) {
                int row = bm0 + c * 8 + (lane >> 3);
                gl_lds16(Ab + (size_t)row * lda + k0 + (lane & 7) * 8, (void*)(As + c * 512));
            } else {
                int cc = c - CA;
                int row = bn0 + cc * 8 + (lane >> 3);
                gl_lds16(Bb + (size_t)row * ldb + k0 + (lane & 7) * 8, (void*)(Bs + cc * 512));
            }
        }
        asm volatile("s_waitcnt vmcnt(0)" ::: "memory");
        __syncthreads();
#pragma unroll
        for (int kk = 0; kk < 2; ++kk) {
            const int kof = kk * 32 + (lane >> 4) * 8;
            bf16x8 af[FM], bfr[FN];
#pragma unroll
            for (int m = 0; m < FM; m++)
                af[m] = *(const bf16x8*)(As + (wr * WTM + m * 16 + (lane & 15)) * 64 + kof);
#pragma unroll
            for (int n = 0; n < FN; n++)
                bfr[n] = *(const bf16x8*)(Bs + (wc * WTN + n * 16 + (lane & 15)) * 64 + kof);
#pragma unroll
            for (int m = 0; m < FM; m++)
#pragma unroll
                for (int n = 0; n < FN; n++)
                    acc[m][n] = __builtin_amdgcn_mfma_f32_16x16x32_bf16(af[m], bfr[n], acc[m][n], 0, 0, 0);
        }
        __syncthreads();
    }

    float* Cf = (float*)Cv;
    unsigned short* Cb = (unsigned short*)Cv;
    const long long cbase = (long long)batch * sC;
#pragma unroll
    for (int m = 0; m < FM; m++) {
#pragma unroll
        for (int n = 0; n < FN; n++) {
            int gr0 = bm0 + wr * WTM + m * 16 + (lane >> 4) * 4;
            int gc = bn0 + wc * WTN + n * 16 + (lane & 15);
#pragma unroll
            for (int j = 0; j < 4; j++) {
                float v = alpha * acc[m][n][j];
                long long idx = cbase + (long long)(gr0 + j) * ldc + gc;
                if constexpr (OMODE == 0) Cf[idx] = v;
                else if constexpr (OMODE == 1) Cb[idx] = f2bf(v);
                else atomicAdd(Cf + idx, v);
            }
        }
    }
}

// ---------------- block reduction helper (256 threads, 4 waves) ----------------
DEVI float block_sum(float v, float* sh) {
    int lane = threadIdx.x & 63, wv = threadIdx.x >> 6;
#pragma unroll
    for (int o = 32; o > 0; o >>= 1) v += __shfl_xor(v, o);
    __syncthreads();
    if (lane == 0) sh[wv] = v;
    __syncthreads();
    return sh[0] + sh[1] + sh[2] + sh[3];
}

// ---------------- softmax over T=4096 (one block per row), out bf16 ----------------
__global__ __launch_bounds__(256) void k_softmax_T(const float* __restrict__ L,
                                                   unsigned short* __restrict__ out) {
    const size_t row = blockIdx.x;
    const float* x = L + row * 4096;
    float v[16];
    float mx = -1e30f;
#pragma unroll
    for (int i = 0; i < 16; i++) {
        v[i] = x[threadIdx.x + i * 256];
        mx = fmaxf(mx, v[i]);
    }
    int lane = threadIdx.x & 63, wv = threadIdx.x >> 6;
#pragma unroll
    for (int o = 32; o > 0; o >>= 1) mx = fmaxf(mx, __shfl_xor(mx, o));
    __shared__ float smax[4], ssum[4];
    if (lane == 0) smax[wv] = mx;
    __syncthreads();
    mx = fmaxf(fmaxf(smax[0], smax[1]), fmaxf(smax[2], smax[3]));
    float sum = 0.f;
#pragma unroll
    for (int i = 0; i < 16; i++) {
        v[i] = __expf(v[i] - mx);
        sum += v[i];
    }
#pragma unroll
    for (int o = 32; o > 0; o >>= 1) sum += __shfl_xor(sum, o);
    if (lane == 0) ssum[wv] = sum;
    __syncthreads();
    float inv = 1.0f / (ssum[0] + ssum[1] + ssum[2] + ssum[3]);
    unsigned short* o = out + row * 4096;
#pragma unroll
    for (int i = 0; i < 16; i++) o[threadIdx.x + i * 256] = f2bf(v[i] * inv);
}

// ---------------- softmax over S=64 (one wave per row), out bf16 ----------------
__global__ __launch_bounds__(256) void k_softmax_S(const float* __restrict__ L,
                                                   unsigned short* __restrict__ out) {
    size_t row = (size_t)blockIdx.x * 4 + (threadIdx.x >> 6);
    int lane = threadIdx.x & 63;
    float v = L[row * 64 + lane];
    float mx = v;
#pragma unroll
    for (int o = 32; o > 0; o >>= 1) mx = fmaxf(mx, __shfl_xor(mx, o));
    float e = __expf(v - mx), sum = e;
#pragma unroll
    for (int o = 32; o > 0; o >>= 1) sum += __shfl_xor(sum, o);
    out[row * 64 + lane] = f2bf(e / sum);
}

// ---------------- updated_slots = LN(slots + out2); write f32 d_out + bf16 ----------------
__global__ __launch_bounds__(256) void k_ln_slots(const float* __restrict__ slot_emb,
                                                  const float* __restrict__ out2,
                                                  const float* __restrict__ w,
                                                  const float* __restrict__ b,
                                                  float* __restrict__ us_out,
                                                  unsigned short* __restrict__ us_b) {
    __shared__ float sh[4];
    int row = blockIdx.x;  // b*64+s
    int s = row & 63;
    float x[16];
    float sum = 0.f;
#pragma unroll
    for (int i = 0; i < 16; i++) {
        int j = threadIdx.x + i * 256;
        x[i] = slot_emb[(size_t)s * 4096 + j] + out2[(size_t)row * 4096 + j];
        sum += x[i];
    }
    sum = block_sum(sum, sh);
    float mu = sum * (1.0f / 4096.0f);
    float s2 = 0.f;
#pragma unroll
    for (int i = 0; i < 16; i++) {
        float d = x[i] - mu;
        s2 += d * d;
    }
    s2 = block_sum(s2, sh);
    float rs = rsqrtf(s2 * (1.0f / 4096.0f) + 1e-5f);
#pragma unroll
    for (int i = 0; i < 16; i++) {
        int j = threadIdx.x + i * 256;
        float y = (x[i] - mu) * rs * w[j] + b[j];
        us_out[(size_t)row * 4096 + j] = y;
        us_b[(size_t)row * 4096 + j] = f2bf(y);
    }
}

// ---------------- fused LN(rout) * gate - seg -> squared error accumulation ----------------
__global__ __launch_bounds__(256) void k_ln_loss(const unsigned short* __restrict__ rout_pre,
                                                 const float* __restrict__ seg,
                                                 const float* __restrict__ w,
                                                 const float* __restrict__ b,
                                                 const float* __restrict__ gate_s,
                                                 double* __restrict__ acc) {
    __shared__ float sh[4];
    size_t row = blockIdx.x;  // 16384 rows
    float x[16];
    float sum = 0.f;
#pragma unroll
    for (int i = 0; i < 16; i++) {
        int j = threadIdx.x + i * 256;
        x[i] = bf2f(rout_pre[row * 4096 + j]);
        sum += x[i];
    }
    sum = block_sum(sum, sh);
    float mu = sum * (1.0f / 4096.0f);
    float s2 = 0.f;
#pragma unroll
    for (int i = 0; i < 16; i++) {
        float d = x[i] - mu;
        s2 += d * d;
    }
    s2 = block_sum(s2, sh);
    float rs = rsqrtf(s2 * (1.0f / 4096.0f) + 1e-5f);
    float g = *gate_s;
    float ls = 0.f;
#pragma unroll
    for (int i = 0; i < 16; i++) {
        int j = threadIdx.x + i * 256;
        float y = (x[i] - mu) * rs * w[j] + b[j];
        float d = g * y - seg[row * 4096 + j];
        ls += d * d;
    }
    ls = block_sum(ls, sh);
    if (threadIdx.x == 0) atomicAdd(acc, (double)ls);
}

// ---------------- gate = sigmoid(mean(gate_bias)) ----------------
__global__ void k_gate(const float* __restrict__ gb, float* __restrict__ gate_s) {
    int lane = threadIdx.x;
    float v = gb[lane];
#pragma unroll
    for (int o = 32; o > 0; o >>= 1) v += __shfl_xor(v, o);
    if (lane == 0) *gate_s = 1.0f / (1.0f + __expf(-(v * (1.0f / 64.0f))));
}

// ---------------- finalize: loss + gate scalars ----------------
__global__ void k_final(const double* __restrict__ acc, const float* __restrict__ gate_s,
                        float* __restrict__ out) {
    if (threadIdx.x == 0) {
        out[1048576] = (float)(*acc * (1.0 / 67108864.0));
        out[1048577] = *gate_s;
    }
}

extern "C" void kernel_launch(void* const* d_in, const int* in_sizes, int n_in,
                              void* d_out, int out_size, void* d_ws, size_t ws_size,
                              hipStream_t stream) {
    const float* seg = (const float*)d_in[0];
    const float* se  = (const float*)d_in[1];
    const float* Wq  = (const float*)d_in[2];
    const float* Wk  = (const float*)d_in[3];
    const float* Wv  = (const float*)d_in[4];
    const float* Wo  = (const float*)d_in[5];
    const float* Wrq = (const float*)d_in[6];
    const float* Wro = (const float*)d_in[7];
    const float* gb  = (const float*)d_in[8];
    const float* snw = (const float*)d_in[9];
    const float* snb = (const float*)d_in[10];
    const float* rnw = (const float*)d_in[11];
    const float* rnb = (const float*)d_in[12];
    float* out = (float*)d_out;

    char* ws = (char*)d_ws;
    size_t off = 0;
    auto alloc = [&](size_t bytes) -> char* {
        char* p = ws + off;
        off += (bytes + 1023) & ~(size_t)1023;
        return p;
    };

    unsigned short* Xb    = (unsigned short*)alloc((size_t)16384 * 4096 * 2);  // later aliased: rout_pre
    unsigned short* KVQ   = (unsigned short*)alloc((size_t)16384 * 768 * 2);
    unsigned short* Wt    = (unsigned short*)alloc((size_t)768 * 4096 * 2);
    unsigned short* Wot   = (unsigned short*)alloc((size_t)4096 * 256 * 2);
    unsigned short* Wrot  = (unsigned short*)alloc((size_t)4096 * 256 * 2);
    unsigned short* qb    = (unsigned short*)alloc((size_t)64 * 256 * 2);
    float*          L1    = (float*)alloc((size_t)4 * 64 * 4096 * 4);          // later aliased: L2
    unsigned short* attn  = (unsigned short*)alloc((size_t)4 * 64 * 4096 * 2);
    unsigned short* Vt    = (unsigned short*)alloc((size_t)4 * 256 * 4096 * 2); // later aliased: rmid
    float*          out1f = (float*)alloc((size_t)4 * 64 * 256 * 4);
    unsigned short* out1b = (unsigned short*)alloc((size_t)4 * 64 * 256 * 2);
    float*          out2  = (float*)alloc((size_t)256 * 4096 * 4);
    unsigned short* usb   = (unsigned short*)alloc((size_t)256 * 4096 * 2);
    float*          rkvf  = (float*)alloc((size_t)256 * 512 * 4);
    unsigned short* rkvb  = (unsigned short*)alloc((size_t)256 * 512 * 2);
    unsigned short* rvt   = (unsigned short*)alloc((size_t)4 * 256 * 64 * 2);
    unsigned short* rattn = (unsigned short*)alloc((size_t)4 * 4096 * 64 * 2);
    float*          gate_s = (float*)alloc(64);
    double*         lacc   = (double*)alloc(64);
    unsigned short* routp = Xb;   // alias: Xb dead after proj GEMM
    float*          L2    = L1;   // alias: L1 dead after softmax_T
    unsigned short* rmid  = Vt;   // alias: Vt dead after attn@V

    hipMemsetAsync(out1f, 0, (size_t)4 * 64 * 256 * 4, stream);
    hipMemsetAsync(rkvf, 0, (size_t)256 * 512 * 4, stream);
    hipMemsetAsync(lacc, 0, 8, stream);

    dim3 tb(32, 8);
    // weight transposes: Wk/Wv/Wrq [4096,256] -> Wt rows 0/256/512; Wo,Wro [256,4096] -> [4096,256]
    k_transpose_f2b<<<dim3(8, 128, 1), tb, 0, stream>>>(Wk, 256, 0, Wt, 4096, 0);
    k_transpose_f2b<<<dim3(8, 128, 1), tb, 0, stream>>>(Wv, 256, 0, Wt + (size_t)256 * 4096, 4096, 0);
    k_transpose_f2b<<<dim3(8, 128, 1), tb, 0, stream>>>(Wrq, 256, 0, Wt + (size_t)512 * 4096, 4096, 0);
    k_transpose_f2b<<<dim3(128, 8, 1), tb, 0, stream>>>(Wo, 4096, 0, Wot, 256, 0);
    k_transpose_f2b<<<dim3(128, 8, 1), tb, 0, stream>>>(Wro, 4096, 0, Wrot, 256, 0);

    // segment_hidden -> bf16
    k_cvt_bf16<<<4096, 256, 0, stream>>>(seg, Xb, (long)67108864);
    // q (batch-invariant: slots are broadcast slot_embeddings)
    k_q<<<64, 256, 0, stream>>>(se, Wq, qb);
    // gate scalar
    k_gate<<<1, 64, 0, stream>>>(gb, gate_s);

    // proj: [16384,4096] @ [4096,768] -> KVQ (cols: K|V|RQ), bf16 out
    k_gemm<128, 128, 2, 2, 1><<<dim3(128, 6, 1), 256, 0, stream>>>(
        Xb, 4096, 0, Wt, 4096, 0, KVQ, 768, 0, 4096, 1, 1.0f);

    // L1 logits: per batch [64,256] @ [4096,256]^T * SCALE -> f32 [64][4096]
    k_gemm<64, 128, 1, 4, 0><<<dim3(1, 32, 4), 256, 0, stream>>>(
        qb, 256, 0, KVQ, 768, 4096LL * 768, L1, 4096, 64LL * 4096, 256, 1, 0.0625f);
    k_softmax_T<<<256, 256, 0, stream>>>(L1, attn);

    // V^T per batch: [4096,256] (ld 768, col off 256) -> [256,4096]
    k_transpose_b2b<<<dim3(8, 128, 4), tb, 0, stream>>>(KVQ + 256, 768, 4096LL * 768, Vt, 4096, 256LL * 4096);

    // attn@V: per batch [64,4096] @ [4096,256], split-K=16, atomic f32
    k_gemm<64, 128, 1, 4, 2><<<dim3(1, 2, 64), 256, 0, stream>>>(
        attn, 4096, 64LL * 4096, Vt, 4096, 256LL * 4096, out1f, 256, 64LL * 256, 4096, 16, 1.0f);
    k_cvt_bf16<<<64, 256, 0, stream>>>(out1f, out1b, (long)65536);

    // out2 = out1 @ Wo : [256,256] @ [256,4096] -> f32
    k_gemm<64, 128, 1, 4, 0><<<dim3(4, 32, 1), 256, 0, stream>>>(
        out1b, 256, 0, Wot, 256, 0, out2, 4096, 0, 256, 1, 1.0f);

    // updated_slots = LN(slots + out2) -> d_out rows + bf16 copy
    k_ln_slots<<<256, 256, 0, stream>>>(se, out2, snw, snb, out, usb);

    // rk|rv = us @ [Wk|Wv] : [256,4096] @ [4096,512], split-K=16, atomic f32
    k_gemm<64, 128, 1, 4, 2><<<dim3(4, 4, 16), 256, 0, stream>>>(
        usb, 4096, 0, Wt, 4096, 0, rkvf, 512, 0, 4096, 16, 1.0f);
    k_cvt_bf16<<<128, 256, 0, stream>>>(rkvf, rkvb, (long)131072);

    // rv^T per batch: [64,256] (ld 512, col off 256) -> [256,64]
    k_transpose_b2b<<<dim3(8, 2, 4), tb, 0, stream>>>(rkvb + 256, 512, 64LL * 512, rvt, 64, 256LL * 64);

    // L2 logits: per batch RQ [4096,256] @ rk[64,256]^T * SCALE -> f32 [4096][64]
    k_gemm<128, 64, 4, 1, 0><<<dim3(32, 1, 4), 256, 0, stream>>>(
        KVQ + 512, 768, 4096LL * 768, rkvb, 512, 64LL * 512, L2, 64, 4096LL * 64, 256, 1, 0.0625f);
    k_softmax_S<<<4096, 256, 0, stream>>>(L2, rattn);

    // rmid = rattn @ rv : per batch [4096,64] @ [64,256] -> bf16
    k_gemm<128, 64, 4, 1, 1><<<dim3(32, 4, 4), 256, 0, stream>>>(
        rattn, 64, 4096LL * 64, rvt, 64, 256LL * 64, rmid, 256, 4096LL * 256, 64, 1, 1.0f);

    // rout_pre = rmid @ Wro : [16384,256] @ [256,4096] -> bf16 (aliased on Xb)
    k_gemm<128, 128, 2, 2, 1><<<dim3(128, 32, 1), 256, 0, stream>>>(
        rmid, 256, 0, Wrot, 256, 0, routp, 4096, 0, 256, 1, 1.0f);

    // fused LN + gate + MSE vs segment
    k_ln_loss<<<16384, 256, 0, stream>>>(routp, seg, rnw, rnb, gate_s, lacc);
    k_final<<<1, 64, 0, stream>>>(lacc, gate_s, out);

    (void)in_sizes; (void)n_in; (void)out_size; (void)ws_size;
}

// Round 2
// 897.871 us; speedup vs baseline: 1.5970x; 1.5970x over previous
//
#include <hip/hip_runtime.h>
#include <hip/hip_bf16.h>

// SlotMemoryCompressor on MI355X (gfx950).
// R1: kill the two whales — k_q (serial SIMT matmul, 425us) -> MFMA splitK GEMM;
// k_ln_loss single-double-atomic (serialized 16K-deep) -> per-block partials +
// final reduce. Vectorize LN kernels (ushort4/float4).

#define DEVI __device__ __forceinline__

typedef __attribute__((ext_vector_type(4))) float f32x4;
typedef __attribute__((ext_vector_type(8))) __bf16 bf16x8;

DEVI float bf2f(unsigned short u) {
    unsigned int x = ((unsigned int)u) << 16;
    return __uint_as_float(x);
}
DEVI unsigned short f2bf(float f) {  // RNE
    unsigned int u = __float_as_uint(f);
    unsigned int r = (u + 0x7FFFu + ((u >> 16) & 1u)) >> 16;
    return (unsigned short)r;
}

DEVI void gl_lds16(const void* g, void* l) {
    __builtin_amdgcn_global_load_lds(
        (const __attribute__((address_space(1))) void*)g,
        (__attribute__((address_space(3))) void*)l, 16, 0, 0);
}

// ---------------- elementwise convert f32 -> bf16 (vector x4) ----------------
__global__ __launch_bounds__(256) void k_cvt_bf16(const float* __restrict__ in,
                                                  unsigned short* __restrict__ out,
                                                  long n) {
    long i = ((long)blockIdx.x * blockDim.x + threadIdx.x) * 4;
    long stride = (long)gridDim.x * blockDim.x * 4;
    for (long j = i; j < n; j += stride) {
        float4 v = *(const float4*)(in + j);
        ushort4 o;
        o.x = f2bf(v.x); o.y = f2bf(v.y); o.z = f2bf(v.z); o.w = f2bf(v.w);
        *(ushort4*)(out + j) = o;
    }
}

// ---------------- transpose f32[R][C] -> bf16[C][R] ----------------
__global__ __launch_bounds__(256) void k_transpose_f2b(const float* __restrict__ in, int ldin, long long sIn,
                                                       unsigned short* __restrict__ out, int ldout, long long sOut) {
    __shared__ float tile[32][33];
    in += (long long)blockIdx.z * sIn;
    out += (long long)blockIdx.z * sOut;
    int c0 = blockIdx.x * 32, r0 = blockIdx.y * 32;
    int tx = threadIdx.x, ty = threadIdx.y;  // (32,8)
#pragma unroll
    for (int i = 0; i < 4; i++)
        tile[ty + i * 8][tx] = in[(size_t)(r0 + ty + i * 8) * ldin + c0 + tx];
    __syncthreads();
#pragma unroll
    for (int i = 0; i < 4; i++)
        out[(size_t)(c0 + ty + i * 8) * ldout + r0 + tx] = f2bf(tile[tx][ty + i * 8]);
}

// ---------------- transpose bf16[R][C] -> bf16[C][R] ----------------
__global__ __launch_bounds__(256) void k_transpose_b2b(const unsigned short* __restrict__ in, int ldin, long long sIn,
                                                       unsigned short* __restrict__ out, int ldout, long long sOut) {
    __shared__ unsigned short tile[32][33];
    in += (long long)blockIdx.z * sIn;
    out += (long long)blockIdx.z * sOut;
    int c0 = blockIdx.x * 32, r0 = blockIdx.y * 32;
    int tx = threadIdx.x, ty = threadIdx.y;
#pragma unroll
    for (int i = 0; i < 4; i++)
        tile[ty + i * 8][tx] = in[(size_t)(r0 + ty + i * 8) * ldin + c0 + tx];
    __syncthreads();
#pragma unroll
    for (int i = 0; i < 4; i++)
        out[(size_t)(c0 + ty + i * 8) * ldout + r0 + tx] = tile[tx][ty + i * 8];
}

// ---------------- templated MFMA GEMM: C = alpha * A[M,K] @ Bt[N,K]^T ----------------
// A,Bt bf16 row-major (lda/ldb in elements, batch strides), BK=64, 4 waves.
// OMODE: 0 = f32 store, 1 = bf16 store, 2 = f32 atomicAdd (split-K partials).
template <int BM, int BN, int WR, int WC, int OMODE>
__global__ __launch_bounds__(256) void k_gemm(const unsigned short* __restrict__ A, int lda, long long sA,
                                              const unsigned short* __restrict__ B, int ldb, long long sB,
                                              void* __restrict__ Cv, int ldc, long long sC,
                                              int K, int ksplit, float alpha) {
    constexpr int NW = WR * WC;
    static_assert(NW == 4, "4 waves");
    __shared__ alignas(1024) unsigned short As[BM * 64];
    __shared__ alignas(1024) unsigned short Bs[BN * 64];
    const int tid = threadIdx.x;
    const int lane = tid & 63;
    const int wv = tid >> 6;
    const int batch = blockIdx.z / ksplit;
    const int ks = blockIdx.z - batch * ksplit;
    const unsigned short* Ab = A + (long long)batch * sA;
    const unsigned short* Bb = B + (long long)batch * sB;
    const int bm0 = blockIdx.x * BM;
    const int bn0 = blockIdx.y * BN;
    const int kchunk = K / ksplit;
    const int kt0 = (ks * kchunk) >> 6;
    const int kt1 = ((ks + 1) * kchunk) >> 6;

    constexpr int WTM = BM / WR, WTN = BN / WC;
    constexpr int FM = WTM / 16, FN = WTN / 16;
    const int wr = wv / WC, wc = wv % WC;

    f32x4 acc[FM][FN] = {};

    constexpr int CA = BM / 8, CB = BN / 8;
    constexpr int PW = (CA + CB) / NW;

    for (int kt = kt0; kt < kt1; ++kt) {
        const int k0 = kt << 6;
#pragma unroll
        for (int i = 0; i < PW; i++) {
            int c = wv * PW + i;
            if (c < CA) {
                int row = bm0 + c * 8 + (lane >> 3);
                gl_lds16(Ab + (size_t)row * lda + k0 + (lane & 7) * 8, (void*)(As + c * 512));
            } else {
                int cc = c - CA;
                int row = bn0 + cc * 8 + (lane >> 3);
                gl_lds16(Bb + (size_t)row * ldb + k0 + (lane & 7) * 8, (void*)(Bs + cc * 512));
            }
        }
        asm volatile("s_waitcnt vmcnt(0)" ::: "memory");
        __syncthreads();
#pragma unroll
        for (int kk = 0; kk < 2; ++kk) {
            const int kof = kk * 32 + (lane >> 4) * 8;
            bf16x8 af[FM], bfr[FN];
#pragma unroll
            for (int m = 0; m < FM; m++)
                af[m] = *(const bf16x8*)(As + (wr * WTM + m * 16 + (lane & 15)) * 64 + kof);
#pragma unroll
            for (int n = 0; n < FN; n++)
                bfr[n] = *(const bf16x8*)(Bs + (wc * WTN + n * 16 + (lane & 15)) * 64 + kof);
#pragma unroll
            for (int m = 0; m < FM; m++)
#pragma unroll
                for (int n = 0; n < FN; n++)
                    acc[m][n] = __builtin_amdgcn_mfma_f32_16x16x32_bf16(af[m], bfr[n], acc[m][n], 0, 0, 0);
        }
        __syncthreads();
    }

    float* Cf = (float*)Cv;
    unsigned short* Cb = (unsigned short*)Cv;
    const long long cbase = (long long)batch * sC;
#pragma unroll
    for (int m = 0; m < FM; m++) {
#pragma unroll
        for (int n = 0; n < FN; n++) {
            int gr0 = bm0 + wr * WTM + m * 16 + (lane >> 4) * 4;
            int gc = bn0 + wc * WTN + n * 16 + (lane & 15);
#pragma unroll
            for (int j = 0; j < 4; j++) {
                float v = alpha * acc[m][n][j];
                long long idx = cbase + (long long)(gr0 + j) * ldc + gc;
                if constexpr (OMODE == 0) Cf[idx] = v;
                else if constexpr (OMODE == 1) Cb[idx] = f2bf(v);
                else atomicAdd(Cf + idx, v);
            }
        }
    }
}

// ---------------- block reduction helper (256 threads, 4 waves) ----------------
DEVI float block_sum(float v, float* sh) {
    int lane = threadIdx.x & 63, wv = threadIdx.x >> 6;
#pragma unroll
    for (int o = 32; o > 0; o >>= 1) v += __shfl_xor(v, o);
    __syncthreads();
    if (lane == 0) sh[wv] = v;
    __syncthreads();
    return sh[0] + sh[1] + sh[2] + sh[3];
}

// ---------------- softmax over T=4096 (one block per row), out bf16 ----------------
__global__ __launch_bounds__(256) void k_softmax_T(const float* __restrict__ L,
                                                   unsigned short* __restrict__ out) {
    const size_t row = blockIdx.x;
    const float* x = L + row * 4096;
    float v[16];
    float mx = -1e30f;
#pragma unroll
    for (int i = 0; i < 4; i++) {
        float4 t = *(const float4*)(x + threadIdx.x * 4 + i * 1024);
        v[i * 4 + 0] = t.x; v[i * 4 + 1] = t.y; v[i * 4 + 2] = t.z; v[i * 4 + 3] = t.w;
        mx = fmaxf(fmaxf(fmaxf(mx, t.x), fmaxf(t.y, t.z)), t.w);
    }
    int lane = threadIdx.x & 63, wv = threadIdx.x >> 6;
#pragma unroll
    for (int o = 32; o > 0; o >>= 1) mx = fmaxf(mx, __shfl_xor(mx, o));
    __shared__ float smax[4], ssum[4];
    if (lane == 0) smax[wv] = mx;
    __syncthreads();
    mx = fmaxf(fmaxf(smax[0], smax[1]), fmaxf(smax[2], smax[3]));
    float sum = 0.f;
#pragma unroll
    for (int i = 0; i < 16; i++) {
        v[i] = __expf(v[i] - mx);
        sum += v[i];
    }
#pragma unroll
    for (int o = 32; o > 0; o >>= 1) sum += __shfl_xor(sum, o);
    if (lane == 0) ssum[wv] = sum;
    __syncthreads();
    float inv = 1.0f / (ssum[0] + ssum[1] + ssum[2] + ssum[3]);
    unsigned short* o = out + row * 4096;
#pragma unroll
    for (int i = 0; i < 4; i++) {
        ushort4 u;
        u.x = f2bf(v[i * 4 + 0] * inv); u.y = f2bf(v[i * 4 + 1] * inv);
        u.z = f2bf(v[i * 4 + 2] * inv); u.w = f2bf(v[i * 4 + 3] * inv);
        *(ushort4*)(o + threadIdx.x * 4 + i * 1024) = u;
    }
}

// ---------------- softmax over S=64 (one wave per row), out bf16 ----------------
__global__ __launch_bounds__(256) void k_softmax_S(const float* __restrict__ L,
                                                   unsigned short* __restrict__ out) {
    size_t row = (size_t)blockIdx.x * 4 + (threadIdx.x >> 6);
    int lane = threadIdx.x & 63;
    float v = L[row * 64 + lane];
    float mx = v;
#pragma unroll
    for (int o = 32; o > 0; o >>= 1) mx = fmaxf(mx, __shfl_xor(mx, o));
    float e = __expf(v - mx), sum = e;
#pragma unroll
    for (int o = 32; o > 0; o >>= 1) sum += __shfl_xor(sum, o);
    out[row * 64 + lane] = f2bf(e / sum);
}

// ---------------- updated_slots = LN(slots + out2); write f32 d_out + bf16 ----------------
__global__ __launch_bounds__(256) void k_ln_slots(const float* __restrict__ slot_emb,
                                                  const float* __restrict__ out2,
                                                  const float* __restrict__ w,
                                                  const float* __restrict__ b,
                                                  float* __restrict__ us_out,
                                                  unsigned short* __restrict__ us_b) {
    __shared__ float sh[4];
    int row = blockIdx.x;  // b*64+s
    int s = row & 63;
    const float* se_r = slot_emb + (size_t)s * 4096;
    const float* o2_r = out2 + (size_t)row * 4096;
    float x[16];
    float sum = 0.f;
#pragma unroll
    for (int i = 0; i < 4; i++) {
        int j0 = threadIdx.x * 4 + i * 1024;
        float4 a = *(const float4*)(se_r + j0);
        float4 c = *(const float4*)(o2_r + j0);
        x[i * 4 + 0] = a.x + c.x; x[i * 4 + 1] = a.y + c.y;
        x[i * 4 + 2] = a.z + c.z; x[i * 4 + 3] = a.w + c.w;
        sum += x[i * 4 + 0] + x[i * 4 + 1] + x[i * 4 + 2] + x[i * 4 + 3];
    }
    sum = block_sum(sum, sh);
    float mu = sum * (1.0f / 4096.0f);
    float s2 = 0.f;
#pragma unroll
    for (int i = 0; i < 16; i++) {
        float d = x[i] - mu;
        s2 += d * d;
    }
    s2 = block_sum(s2, sh);
    float rs = rsqrtf(s2 * (1.0f / 4096.0f) + 1e-5f);
#pragma unroll
    for (int i = 0; i < 4; i++) {
        int j0 = threadIdx.x * 4 + i * 1024;
        float4 wv4 = *(const float4*)(w + j0);
        float4 bv4 = *(const float4*)(b + j0);
        float4 y;
        y.x = (x[i * 4 + 0] - mu) * rs * wv4.x + bv4.x;
        y.y = (x[i * 4 + 1] - mu) * rs * wv4.y + bv4.y;
        y.z = (x[i * 4 + 2] - mu) * rs * wv4.z + bv4.z;
        y.w = (x[i * 4 + 3] - mu) * rs * wv4.w + bv4.w;
        *(float4*)(us_out + (size_t)row * 4096 + j0) = y;
        ushort4 u;
        u.x = f2bf(y.x); u.y = f2bf(y.y); u.z = f2bf(y.z); u.w = f2bf(y.w);
        *(ushort4*)(us_b + (size_t)row * 4096 + j0) = u;
    }
}

// ---------------- fused LN(rout)*gate - seg -> squared error per-block partial ----------------
__global__ __launch_bounds__(256) void k_ln_loss(const unsigned short* __restrict__ rout_pre,
                                                 const float* __restrict__ seg,
                                                 const float* __restrict__ w,
                                                 const float* __restrict__ b,
                                                 const float* __restrict__ gate_s,
                                                 float* __restrict__ partials) {
    __shared__ float sh[4];
    size_t row = blockIdx.x;  // 16384 rows
    const unsigned short* xr = rout_pre + row * 4096;
    const float* sr = seg + row * 4096;
    float x[16];
    float sum = 0.f;
#pragma unroll
    for (int i = 0; i < 4; i++) {
        int j0 = threadIdx.x * 4 + i * 1024;
        ushort4 u = *(const ushort4*)(xr + j0);
        x[i * 4 + 0] = bf2f(u.x); x[i * 4 + 1] = bf2f(u.y);
        x[i * 4 + 2] = bf2f(u.z); x[i * 4 + 3] = bf2f(u.w);
        sum += x[i * 4 + 0] + x[i * 4 + 1] + x[i * 4 + 2] + x[i * 4 + 3];
    }
    sum = block_sum(sum, sh);
    float mu = sum * (1.0f / 4096.0f);
    float s2 = 0.f;
#pragma unroll
    for (int i = 0; i < 16; i++) {
        float d = x[i] - mu;
        s2 += d * d;
    }
    s2 = block_sum(s2, sh);
    float rs = rsqrtf(s2 * (1.0f / 4096.0f) + 1e-5f);
    float g = *gate_s;
    float ls = 0.f;
#pragma unroll
    for (int i = 0; i < 4; i++) {
        int j0 = threadIdx.x * 4 + i * 1024;
        float4 wv4 = *(const float4*)(w + j0);
        float4 bv4 = *(const float4*)(b + j0);
        float4 sv4 = *(const float4*)(sr + j0);
        float d0 = g * ((x[i * 4 + 0] - mu) * rs * wv4.x + bv4.x) - sv4.x;
        float d1 = g * ((x[i * 4 + 1] - mu) * rs * wv4.y + bv4.y) - sv4.y;
        float d2 = g * ((x[i * 4 + 2] - mu) * rs * wv4.z + bv4.z) - sv4.z;
        float d3 = g * ((x[i * 4 + 3] - mu) * rs * wv4.w + bv4.w) - sv4.w;
        ls += d0 * d0 + d1 * d1 + d2 * d2 + d3 * d3;
    }
    ls = block_sum(ls, sh);
    if (threadIdx.x == 0) partials[row] = ls;
}

// ---------------- gate = sigmoid(mean(gate_bias)) ----------------
__global__ void k_gate(const float* __restrict__ gb, float* __restrict__ gate_s) {
    int lane = threadIdx.x;
    float v = gb[lane];
#pragma unroll
    for (int o = 32; o > 0; o >>= 1) v += __shfl_xor(v, o);
    if (lane == 0) *gate_s = 1.0f / (1.0f + __expf(-(v * (1.0f / 64.0f))));
}

// ---------------- finalize: reduce 16384 partials -> loss; write gate ----------------
__global__ __launch_bounds__(1024) void k_loss_final(const float* __restrict__ partials,
                                                     const float* __restrict__ gate_s,
                                                     float* __restrict__ out) {
    __shared__ float sh[16];
    int t = threadIdx.x;
    float s = 0.f;
#pragma unroll
    for (int i = 0; i < 4; i++) {
        float4 v = *(const float4*)(partials + t * 16 + i * 4);
        s += v.x + v.y + v.z + v.w;
    }
#pragma unroll
    for (int o = 32; o > 0; o >>= 1) s += __shfl_xor(s, o);
    int lane = t & 63, wv = t >> 6;
    if (lane == 0) sh[wv] = s;
    __syncthreads();
    if (t == 0) {
        float tot = 0.f;
#pragma unroll
        for (int i = 0; i < 16; i++) tot += sh[i];
        out[1048576] = tot * (1.0f / 67108864.0f);
        out[1048577] = *gate_s;
    }
}

extern "C" void kernel_launch(void* const* d_in, const int* in_sizes, int n_in,
                              void* d_out, int out_size, void* d_ws, size_t ws_size,
                              hipStream_t stream) {
    const float* seg = (const float*)d_in[0];
    const float* se  = (const float*)d_in[1];
    const float* Wq  = (const float*)d_in[2];
    const float* Wk  = (const float*)d_in[3];
    const float* Wv  = (const float*)d_in[4];
    const float* Wo  = (const float*)d_in[5];
    const float* Wrq = (const float*)d_in[6];
    const float* Wro = (const float*)d_in[7];
    const float* gb  = (const float*)d_in[8];
    const float* snw = (const float*)d_in[9];
    const float* snb = (const float*)d_in[10];
    const float* rnw = (const float*)d_in[11];
    const float* rnb = (const float*)d_in[12];
    float* out = (float*)d_out;

    char* ws = (char*)d_ws;
    size_t off = 0;
    auto alloc = [&](size_t bytes) -> char* {
        char* p = ws + off;
        off += (bytes + 1023) & ~(size_t)1023;
        return p;
    };

    unsigned short* Xb    = (unsigned short*)alloc((size_t)16384 * 4096 * 2);  // later aliased: rout_pre
    unsigned short* KVQ   = (unsigned short*)alloc((size_t)16384 * 768 * 2);
    unsigned short* Wt    = (unsigned short*)alloc((size_t)1024 * 4096 * 2);   // K|V|RQ|Q slabs
    unsigned short* Wot   = (unsigned short*)alloc((size_t)4096 * 256 * 2);
    unsigned short* Wrot  = (unsigned short*)alloc((size_t)4096 * 256 * 2);
    unsigned short* seb   = (unsigned short*)alloc((size_t)64 * 4096 * 2);
    float*          qf    = (float*)alloc((size_t)64 * 256 * 4);
    unsigned short* qb    = (unsigned short*)alloc((size_t)64 * 256 * 2);
    float*          L1    = (float*)alloc((size_t)4 * 64 * 4096 * 4);          // later aliased: L2
    unsigned short* attn  = (unsigned short*)alloc((size_t)4 * 64 * 4096 * 2);
    unsigned short* Vt    = (unsigned short*)alloc((size_t)4 * 256 * 4096 * 2); // later aliased: rmid
    float*          out1f = (float*)alloc((size_t)4 * 64 * 256 * 4);
    unsigned short* out1b = (unsigned short*)alloc((size_t)4 * 64 * 256 * 2);
    float*          out2  = (float*)alloc((size_t)256 * 4096 * 4);
    unsigned short* usb   = (unsigned short*)alloc((size_t)256 * 4096 * 2);
    float*          rkvf  = (float*)alloc((size_t)256 * 512 * 4);
    unsigned short* rkvb  = (unsigned short*)alloc((size_t)256 * 512 * 2);
    unsigned short* rvt   = (unsigned short*)alloc((size_t)4 * 256 * 64 * 2);
    unsigned short* rattn = (unsigned short*)alloc((size_t)4 * 4096 * 64 * 2);
    float*          gate_s = (float*)alloc(64);
    float*          partials = (float*)alloc((size_t)16384 * 4);
    unsigned short* routp = Xb;   // alias: Xb dead after proj GEMM
    float*          L2    = L1;   // alias: L1 dead after softmax_T
    unsigned short* rmid  = Vt;   // alias: Vt dead after attn@V

    hipMemsetAsync(out1f, 0, (size_t)4 * 64 * 256 * 4, stream);
    hipMemsetAsync(rkvf, 0, (size_t)256 * 512 * 4, stream);
    hipMemsetAsync(qf, 0, (size_t)64 * 256 * 4, stream);

    dim3 tb(32, 8);
    // weight transposes: Wk/Wv/Wrq/Wq [4096,256] -> Wt slabs; Wo,Wro [256,4096] -> [4096,256]
    k_transpose_f2b<<<dim3(8, 128, 1), tb, 0, stream>>>(Wk, 256, 0, Wt, 4096, 0);
    k_transpose_f2b<<<dim3(8, 128, 1), tb, 0, stream>>>(Wv, 256, 0, Wt + (size_t)256 * 4096, 4096, 0);
    k_transpose_f2b<<<dim3(8, 128, 1), tb, 0, stream>>>(Wrq, 256, 0, Wt + (size_t)512 * 4096, 4096, 0);
    k_transpose_f2b<<<dim3(8, 128, 1), tb, 0, stream>>>(Wq, 256, 0, Wt + (size_t)768 * 4096, 4096, 0);
    k_transpose_f2b<<<dim3(128, 8, 1), tb, 0, stream>>>(Wo, 4096, 0, Wot, 256, 0);
    k_transpose_f2b<<<dim3(128, 8, 1), tb, 0, stream>>>(Wro, 4096, 0, Wrot, 256, 0);

    // conversions
    k_cvt_bf16<<<4096, 256, 0, stream>>>(seg, Xb, (long)67108864);
    k_cvt_bf16<<<256, 256, 0, stream>>>(se, seb, (long)262144);
    k_gate<<<1, 64, 0, stream>>>(gb, gate_s);

    // q = se @ Wq : [64,4096] @ [4096,256], split-K=16, atomic f32 -> bf16
    k_gemm<64, 128, 1, 4, 2><<<dim3(1, 2, 16), 256, 0, stream>>>(
        seb, 4096, 0, Wt + (size_t)768 * 4096, 4096, 0, qf, 256, 0, 4096, 16, 1.0f);
    k_cvt_bf16<<<16, 256, 0, stream>>>(qf, qb, (long)16384);

    // proj: [16384,4096] @ [4096,768] -> KVQ (cols: K|V|RQ), bf16 out
    k_gemm<128, 128, 2, 2, 1><<<dim3(128, 6, 1), 256, 0, stream>>>(
        Xb, 4096, 0, Wt, 4096, 0, KVQ, 768, 0, 4096, 1, 1.0f);

    // L1 logits: per batch [64,256] @ [4096,256]^T * SCALE -> f32 [64][4096]
    k_gemm<64, 128, 1, 4, 0><<<dim3(1, 32, 4), 256, 0, stream>>>(
        qb, 256, 0, KVQ, 768, 4096LL * 768, L1, 4096, 64LL * 4096, 256, 1, 0.0625f);
    k_softmax_T<<<256, 256, 0, stream>>>(L1, attn);

    // V^T per batch: [4096,256] (ld 768, col off 256) -> [256,4096]
    k_transpose_b2b<<<dim3(8, 128, 4), tb, 0, stream>>>(KVQ + 256, 768, 4096LL * 768, Vt, 4096, 256LL * 4096);

    // attn@V: per batch [64,4096] @ [4096,256], split-K=16, atomic f32
    k_gemm<64, 128, 1, 4, 2><<<dim3(1, 2, 64), 256, 0, stream>>>(
        attn, 4096, 64LL * 4096, Vt, 4096, 256LL * 4096, out1f, 256, 64LL * 256, 4096, 16, 1.0f);
    k_cvt_bf16<<<64, 256, 0, stream>>>(out1f, out1b, (long)65536);

    // out2 = out1 @ Wo : [256,256] @ [256,4096] -> f32
    k_gemm<64, 128, 1, 4, 0><<<dim3(4, 32, 1), 256, 0, stream>>>(
        out1b, 256, 0, Wot, 256, 0, out2, 4096, 0, 256, 1, 1.0f);

    // updated_slots = LN(slots + out2) -> d_out rows + bf16 copy
    k_ln_slots<<<256, 256, 0, stream>>>(se, out2, snw, snb, out, usb);

    // rk|rv = us @ [Wk|Wv] : [256,4096] @ [4096,512], split-K=16, atomic f32
    k_gemm<64, 128, 1, 4, 2><<<dim3(4, 4, 16), 256, 0, stream>>>(
        usb, 4096, 0, Wt, 4096, 0, rkvf, 512, 0, 4096, 16, 1.0f);
    k_cvt_bf16<<<128, 256, 0, stream>>>(rkvf, rkvb, (long)131072);

    // rv^T per batch: [64,256] (ld 512, col off 256) -> [256,64]
    k_transpose_b2b<<<dim3(8, 2, 4), tb, 0, stream>>>(rkvb + 256, 512, 64LL * 512, rvt, 64, 256LL * 64);

    // L2 logits: per batch RQ [4096,256] @ rk[64,256]^T * SCALE -> f32 [4096][64]
    k_gemm<128, 64, 4, 1, 0><<<dim3(32, 1, 4), 256, 0, stream>>>(
        KVQ + 512, 768, 4096LL * 768, L2 /*dummy reuse*/ == nullptr ? nullptr : rkvb, 512, 64LL * 512, L2, 64, 4096LL * 64, 256, 1, 0.0625f);
    k_softmax_S<<<4096, 256, 0, stream>>>(L2, rattn);

    // rmid = rattn @ rv : per batch [4096,64] @ [64,256] -> bf16
    k_gemm<128, 64, 4, 1, 1><<<dim3(32, 4, 4), 256, 0, stream>>>(
        rattn, 64, 4096LL * 64, rvt, 64, 256LL * 64, rmid, 256, 4096LL * 256, 64, 1, 1.0f);

    // rout_pre = rmid @ Wro : [16384,256] @ [256,4096] -> bf16 (aliased on Xb)
    k_gemm<128, 128, 2, 2, 1><<<dim3(128, 32, 1), 256, 0, stream>>>(
        rmid, 256, 0, Wrot, 256, 0, routp, 4096, 0, 256, 1, 1.0f);

    // fused LN + gate + MSE vs segment -> partials, then final reduce
    k_ln_loss<<<16384, 256, 0, stream>>>(routp, seg, rnw, rnb, gate_s, partials);
    k_loss_final<<<1, 1024, 0, stream>>>(partials, gate_s, out);

    (void)in_sizes; (void)n_in; (void)out_size; (void)ws_size;
}

// Round 3
// 785.488 us; speedup vs baseline: 1.8255x; 1.1431x over previous
//
#include <hip/hip_runtime.h>
#include <hip/hip_bf16.h>

// SlotMemoryCompressor on MI355X (gfx950).
// R2: GEMM rewritten as 2-phase double-buffered pipeline (stage-next-early,
// counted vmcnt, raw s_barrier — never drain vmcnt to 0 in the loop) with
// both-sides XOR bank-conflict swizzle (linear LDS dest + inverse-swizzled
// global source + swizzled ds_read). XCD swizzle on blockIdx.x. Vectorized
// ushort8 transpose.

#define DEVI __device__ __forceinline__

typedef __attribute__((ext_vector_type(4))) float f32x4;
typedef __attribute__((ext_vector_type(8))) __bf16 bf16x8;
typedef __attribute__((ext_vector_type(8))) unsigned short u16x8;

DEVI float bf2f(unsigned short u) {
    unsigned int x = ((unsigned int)u) << 16;
    return __uint_as_float(x);
}
DEVI unsigned short f2bf(float f) {  // RNE
    unsigned int u = __float_as_uint(f);
    unsigned int r = (u + 0x7FFFu + ((u >> 16) & 1u)) >> 16;
    return (unsigned short)r;
}

DEVI void gl_lds16(const void* g, void* l) {
    __builtin_amdgcn_global_load_lds(
        (const __attribute__((address_space(1))) void*)g,
        (__attribute__((address_space(3))) void*)l, 16, 0, 0);
}

// ---------------- elementwise convert f32 -> bf16 (vector x4) ----------------
__global__ __launch_bounds__(256) void k_cvt_bf16(const float* __restrict__ in,
                                                  unsigned short* __restrict__ out,
                                                  long n) {
    long i = ((long)blockIdx.x * blockDim.x + threadIdx.x) * 4;
    long stride = (long)gridDim.x * blockDim.x * 4;
    for (long j = i; j < n; j += stride) {
        float4 v = *(const float4*)(in + j);
        ushort4 o;
        o.x = f2bf(v.x); o.y = f2bf(v.y); o.z = f2bf(v.z); o.w = f2bf(v.w);
        *(ushort4*)(out + j) = o;
    }
}

// ---------------- transpose f32[R][C] -> bf16[C][R] (weights, small) ----------------
__global__ __launch_bounds__(256) void k_transpose_f2b(const float* __restrict__ in, int ldin, long long sIn,
                                                       unsigned short* __restrict__ out, int ldout, long long sOut) {
    __shared__ float tile[32][33];
    in += (long long)blockIdx.z * sIn;
    out += (long long)blockIdx.z * sOut;
    int c0 = blockIdx.x * 32, r0 = blockIdx.y * 32;
    int tx = threadIdx.x, ty = threadIdx.y;  // (32,8)
#pragma unroll
    for (int i = 0; i < 4; i++)
        tile[ty + i * 8][tx] = in[(size_t)(r0 + ty + i * 8) * ldin + c0 + tx];
    __syncthreads();
#pragma unroll
    for (int i = 0; i < 4; i++)
        out[(size_t)(c0 + ty + i * 8) * ldout + r0 + tx] = f2bf(tile[tx][ty + i * 8]);
}

// ---------------- transpose bf16[R][C] -> bf16[C][R], 64x64 tiles, u16x8 ----------------
__global__ __launch_bounds__(256) void k_transpose_b2b(const unsigned short* __restrict__ in, int ldin, long long sIn,
                                                       unsigned short* __restrict__ out, int ldout, long long sOut) {
    __shared__ unsigned short tile[64][72];  // 72*2=144B row pitch (16B-aligned)
    in += (long long)blockIdx.z * sIn;
    out += (long long)blockIdx.z * sOut;
    int c0 = blockIdx.x * 64, r0 = blockIdx.y * 64;
    int t = threadIdx.x;
    int r = t >> 2, cc = (t & 3) * 16;
    u16x8 v0 = *(const u16x8*)(in + (size_t)(r0 + r) * ldin + c0 + cc);
    u16x8 v1 = *(const u16x8*)(in + (size_t)(r0 + r) * ldin + c0 + cc + 8);
    *(u16x8*)(&tile[r][cc]) = v0;
    *(u16x8*)(&tile[r][cc + 8]) = v1;
    __syncthreads();
    int c = t >> 2, rr = (t & 3) * 16;
    u16x8 w0, w1;
#pragma unroll
    for (int j = 0; j < 8; j++) w0[j] = tile[rr + j][c];
#pragma unroll
    for (int j = 0; j < 8; j++) w1[j] = tile[rr + 8 + j][c];
    *(u16x8*)(out + (size_t)(c0 + c) * ldout + r0 + rr) = w0;
    *(u16x8*)(out + (size_t)(c0 + c) * ldout + r0 + rr + 8) = w1;
}

// ---------------- MFMA GEMM: C = alpha * A[M,K] @ Bt[N,K]^T ----------------
// 2-phase double-buffered: stage(next) early, counted vmcnt (never 0 in loop),
// raw s_barrier; both-sides XOR swizzle kills LDS bank conflicts.
// OMODE: 0 = f32 store, 1 = bf16 store, 2 = f32 atomicAdd (split-K partials).
template <int BM, int BN, int WR, int WC, int OMODE, int XSWZ>
__global__ __launch_bounds__(256) void k_gemm(const unsigned short* __restrict__ A, int lda, long long sA,
                                              const unsigned short* __restrict__ B, int ldb, long long sB,
                                              void* __restrict__ Cv, int ldc, long long sC,
                                              int K, int ksplit, float alpha) {
    constexpr int NW = WR * WC;
    static_assert(NW == 4, "4 waves");
    __shared__ alignas(1024) unsigned short As[2][BM * 64];
    __shared__ alignas(1024) unsigned short Bs[2][BN * 64];
    const int tid = threadIdx.x;
    const int lane = tid & 63;
    const int wv = tid >> 6;
    int bx = blockIdx.x;
    if (XSWZ) bx = (bx & 7) * ((int)gridDim.x >> 3) + (bx >> 3);  // XCD chunking (gridDim.x%8==0)
    const int batch = blockIdx.z / ksplit;
    const int ks = blockIdx.z - batch * ksplit;
    const unsigned short* Ab = A + (long long)batch * sA;
    const unsigned short* Bb = B + (long long)batch * sB;
    const int bm0 = bx * BM;
    const int bn0 = blockIdx.y * BN;
    const int kchunk = K / ksplit;
    const int kt0 = (ks * kchunk) >> 6;
    const int kt1 = ((ks + 1) * kchunk) >> 6;

    constexpr int WTM = BM / WR, WTN = BN / WC;
    constexpr int FM = WTM / 16, FN = WTN / 16;
    const int wr = wv / WC, wc = wv % WC;

    f32x4 acc[FM][FN] = {};

    constexpr int CA = BM / 8, CB = BN / 8;
    constexpr int PW = (CA + CB) / NW;  // gl_lds issues per thread per K-step

    // inverse swizzle on the GLOBAL source (elements); LDS dest stays linear
    const int srcswz = 8 * ((lane & 7) ^ (lane >> 3));
    const int rlane = lane >> 3;

    // precomputed swizzled ds_read element offsets
    int aof[2][FM], bof[2][FN];
#pragma unroll
    for (int kk = 0; kk < 2; kk++) {
        const int kofs = kk * 32 + (lane >> 4) * 8;
#pragma unroll
        for (int m = 0; m < FM; m++) {
            int r = wr * WTM + m * 16 + (lane & 15);
            aof[kk][m] = r * 64 + (kofs ^ ((r & 7) << 3));
        }
#pragma unroll
        for (int n = 0; n < FN; n++) {
            int r = wc * WTN + n * 16 + (lane & 15);
            bof[kk][n] = r * 64 + (kofs ^ ((r & 7) << 3));
        }
    }

    auto stage = [&](int buf, int kt) {
        const int k0 = kt << 6;
#pragma unroll
        for (int i = 0; i < PW; i++) {
            int c = wv * PW + i;
            if (c < CA) {
                int row = bm0 + c * 8 + rlane;
                gl_lds16(Ab + (size_t)row * lda + k0 + srcswz, (void*)(As[buf] + c * 512));
            } else {
                int cc = c - CA;
                int row = bn0 + cc * 8 + rlane;
                gl_lds16(Bb + (size_t)row * ldb + k0 + srcswz, (void*)(Bs[buf] + cc * 512));
            }
        }
    };

    stage(0, kt0);
    int cur = 0;
    for (int kt = kt0; kt < kt1; ++kt) {
        const bool hasnext = (kt + 1 < kt1);
        if (hasnext) {
            stage(cur ^ 1, kt + 1);
            if constexpr (PW == 8) asm volatile("s_waitcnt vmcnt(8)" ::: "memory");
            else if constexpr (PW == 6) asm volatile("s_waitcnt vmcnt(6)" ::: "memory");
            else asm volatile("s_waitcnt vmcnt(0)" ::: "memory");
        } else {
            asm volatile("s_waitcnt vmcnt(0)" ::: "memory");
        }
        __builtin_amdgcn_s_barrier();
        asm volatile("" ::: "memory");
        const unsigned short* Ac = As[cur];
        const unsigned short* Bc = Bs[cur];
#pragma unroll
        for (int kk = 0; kk < 2; ++kk) {
            bf16x8 af[FM], bfr[FN];
#pragma unroll
            for (int m = 0; m < FM; m++) af[m] = *(const bf16x8*)(Ac + aof[kk][m]);
#pragma unroll
            for (int n = 0; n < FN; n++) bfr[n] = *(const bf16x8*)(Bc + bof[kk][n]);
#pragma unroll
            for (int m = 0; m < FM; m++)
#pragma unroll
                for (int n = 0; n < FN; n++)
                    acc[m][n] = __builtin_amdgcn_mfma_f32_16x16x32_bf16(af[m], bfr[n], acc[m][n], 0, 0, 0);
        }
        asm volatile("" ::: "memory");
        __builtin_amdgcn_s_barrier();
        cur ^= 1;
    }

    float* Cf = (float*)Cv;
    unsigned short* Cb = (unsigned short*)Cv;
    const long long cbase = (long long)batch * sC;
#pragma unroll
    for (int m = 0; m < FM; m++) {
#pragma unroll
        for (int n = 0; n < FN; n++) {
            int gr0 = bm0 + wr * WTM + m * 16 + (lane >> 4) * 4;
            int gc = bn0 + wc * WTN + n * 16 + (lane & 15);
#pragma unroll
            for (int j = 0; j < 4; j++) {
                float v = alpha * acc[m][n][j];
                long long idx = cbase + (long long)(gr0 + j) * ldc + gc;
                if constexpr (OMODE == 0) Cf[idx] = v;
                else if constexpr (OMODE == 1) Cb[idx] = f2bf(v);
                else atomicAdd(Cf + idx, v);
            }
        }
    }
}

// ---------------- block reduction helper (256 threads, 4 waves) ----------------
DEVI float block_sum(float v, float* sh) {
    int lane = threadIdx.x & 63, wv = threadIdx.x >> 6;
#pragma unroll
    for (int o = 32; o > 0; o >>= 1) v += __shfl_xor(v, o);
    __syncthreads();
    if (lane == 0) sh[wv] = v;
    __syncthreads();
    return sh[0] + sh[1] + sh[2] + sh[3];
}

// ---------------- softmax over T=4096 (one block per row), out bf16 ----------------
__global__ __launch_bounds__(256) void k_softmax_T(const float* __restrict__ L,
                                                   unsigned short* __restrict__ out) {
    const size_t row = blockIdx.x;
    const float* x = L + row * 4096;
    float v[16];
    float mx = -1e30f;
#pragma unroll
    for (int i = 0; i < 4; i++) {
        float4 t = *(const float4*)(x + threadIdx.x * 4 + i * 1024);
        v[i * 4 + 0] = t.x; v[i * 4 + 1] = t.y; v[i * 4 + 2] = t.z; v[i * 4 + 3] = t.w;
        mx = fmaxf(fmaxf(fmaxf(mx, t.x), fmaxf(t.y, t.z)), t.w);
    }
    int lane = threadIdx.x & 63, wv = threadIdx.x >> 6;
#pragma unroll
    for (int o = 32; o > 0; o >>= 1) mx = fmaxf(mx, __shfl_xor(mx, o));
    __shared__ float smax[4], ssum[4];
    if (lane == 0) smax[wv] = mx;
    __syncthreads();
    mx = fmaxf(fmaxf(smax[0], smax[1]), fmaxf(smax[2], smax[3]));
    float sum = 0.f;
#pragma unroll
    for (int i = 0; i < 16; i++) {
        v[i] = __expf(v[i] - mx);
        sum += v[i];
    }
#pragma unroll
    for (int o = 32; o > 0; o >>= 1) sum += __shfl_xor(sum, o);
    if (lane == 0) ssum[wv] = sum;
    __syncthreads();
    float inv = 1.0f / (ssum[0] + ssum[1] + ssum[2] + ssum[3]);
    unsigned short* o = out + row * 4096;
#pragma unroll
    for (int i = 0; i < 4; i++) {
        ushort4 u;
        u.x = f2bf(v[i * 4 + 0] * inv); u.y = f2bf(v[i * 4 + 1] * inv);
        u.z = f2bf(v[i * 4 + 2] * inv); u.w = f2bf(v[i * 4 + 3] * inv);
        *(ushort4*)(o + threadIdx.x * 4 + i * 1024) = u;
    }
}

// ---------------- softmax over S=64 (one wave per row), out bf16 ----------------
__global__ __launch_bounds__(256) void k_softmax_S(const float* __restrict__ L,
                                                   unsigned short* __restrict__ out) {
    size_t row = (size_t)blockIdx.x * 4 + (threadIdx.x >> 6);
    int lane = threadIdx.x & 63;
    float v = L[row * 64 + lane];
    float mx = v;
#pragma unroll
    for (int o = 32; o > 0; o >>= 1) mx = fmaxf(mx, __shfl_xor(mx, o));
    float e = __expf(v - mx), sum = e;
#pragma unroll
    for (int o = 32; o > 0; o >>= 1) sum += __shfl_xor(sum, o);
    out[row * 64 + lane] = f2bf(e / sum);
}

// ---------------- updated_slots = LN(slots + out2); write f32 d_out + bf16 ----------------
__global__ __launch_bounds__(256) void k_ln_slots(const float* __restrict__ slot_emb,
                                                  const float* __restrict__ out2,
                                                  const float* __restrict__ w,
                                                  const float* __restrict__ b,
                                                  float* __restrict__ us_out,
                                                  unsigned short* __restrict__ us_b) {
    __shared__ float sh[4];
    int row = blockIdx.x;  // b*64+s
    int s = row & 63;
    const float* se_r = slot_emb + (size_t)s * 4096;
    const float* o2_r = out2 + (size_t)row * 4096;
    float x[16];
    float sum = 0.f;
#pragma unroll
    for (int i = 0; i < 4; i++) {
        int j0 = threadIdx.x * 4 + i * 1024;
        float4 a = *(const float4*)(se_r + j0);
        float4 c = *(const float4*)(o2_r + j0);
        x[i * 4 + 0] = a.x + c.x; x[i * 4 + 1] = a.y + c.y;
        x[i * 4 + 2] = a.z + c.z; x[i * 4 + 3] = a.w + c.w;
        sum += x[i * 4 + 0] + x[i * 4 + 1] + x[i * 4 + 2] + x[i * 4 + 3];
    }
    sum = block_sum(sum, sh);
    float mu = sum * (1.0f / 4096.0f);
    float s2 = 0.f;
#pragma unroll
    for (int i = 0; i < 16; i++) {
        float d = x[i] - mu;
        s2 += d * d;
    }
    s2 = block_sum(s2, sh);
    float rs = rsqrtf(s2 * (1.0f / 4096.0f) + 1e-5f);
#pragma unroll
    for (int i = 0; i < 4; i++) {
        int j0 = threadIdx.x * 4 + i * 1024;
        float4 wv4 = *(const float4*)(w + j0);
        float4 bv4 = *(const float4*)(b + j0);
        float4 y;
        y.x = (x[i * 4 + 0] - mu) * rs * wv4.x + bv4.x;
        y.y = (x[i * 4 + 1] - mu) * rs * wv4.y + bv4.y;
        y.z = (x[i * 4 + 2] - mu) * rs * wv4.z + bv4.z;
        y.w = (x[i * 4 + 3] - mu) * rs * wv4.w + bv4.w;
        *(float4*)(us_out + (size_t)row * 4096 + j0) = y;
        ushort4 u;
        u.x = f2bf(y.x); u.y = f2bf(y.y); u.z = f2bf(y.z); u.w = f2bf(y.w);
        *(ushort4*)(us_b + (size_t)row * 4096 + j0) = u;
    }
}

// ---------------- fused LN(rout)*gate - seg -> squared error per-block partial ----------------
__global__ __launch_bounds__(256) void k_ln_loss(const unsigned short* __restrict__ rout_pre,
                                                 const float* __restrict__ seg,
                                                 const float* __restrict__ w,
                                                 const float* __restrict__ b,
                                                 const float* __restrict__ gate_s,
                                                 float* __restrict__ partials) {
    __shared__ float sh[4];
    size_t row = blockIdx.x;  // 16384 rows
    const unsigned short* xr = rout_pre + row * 4096;
    const float* sr = seg + row * 4096;
    float x[16];
    float sum = 0.f;
#pragma unroll
    for (int i = 0; i < 4; i++) {
        int j0 = threadIdx.x * 4 + i * 1024;
        ushort4 u = *(const ushort4*)(xr + j0);
        x[i * 4 + 0] = bf2f(u.x); x[i * 4 + 1] = bf2f(u.y);
        x[i * 4 + 2] = bf2f(u.z); x[i * 4 + 3] = bf2f(u.w);
        sum += x[i * 4 + 0] + x[i * 4 + 1] + x[i * 4 + 2] + x[i * 4 + 3];
    }
    sum = block_sum(sum, sh);
    float mu = sum * (1.0f / 4096.0f);
    float s2 = 0.f;
#pragma unroll
    for (int i = 0; i < 16; i++) {
        float d = x[i] - mu;
        s2 += d * d;
    }
    s2 = block_sum(s2, sh);
    float rs = rsqrtf(s2 * (1.0f / 4096.0f) + 1e-5f);
    float g = *gate_s;
    float ls = 0.f;
#pragma unroll
    for (int i = 0; i < 4; i++) {
        int j0 = threadIdx.x * 4 + i * 1024;
        float4 wv4 = *(const float4*)(w + j0);
        float4 bv4 = *(const float4*)(b + j0);
        float4 sv4 = *(const float4*)(sr + j0);
        float d0 = g * ((x[i * 4 + 0] - mu) * rs * wv4.x + bv4.x) - sv4.x;
        float d1 = g * ((x[i * 4 + 1] - mu) * rs * wv4.y + bv4.y) - sv4.y;
        float d2 = g * ((x[i * 4 + 2] - mu) * rs * wv4.z + bv4.z) - sv4.z;
        float d3 = g * ((x[i * 4 + 3] - mu) * rs * wv4.w + bv4.w) - sv4.w;
        ls += d0 * d0 + d1 * d1 + d2 * d2 + d3 * d3;
    }
    ls = block_sum(ls, sh);
    if (threadIdx.x == 0) partials[row] = ls;
}

// ---------------- gate = sigmoid(mean(gate_bias)) ----------------
__global__ void k_gate(const float* __restrict__ gb, float* __restrict__ gate_s) {
    int lane = threadIdx.x;
    float v = gb[lane];
#pragma unroll
    for (int o = 32; o > 0; o >>= 1) v += __shfl_xor(v, o);
    if (lane == 0) *gate_s = 1.0f / (1.0f + __expf(-(v * (1.0f / 64.0f))));
}

// ---------------- finalize: reduce 16384 partials -> loss; write gate ----------------
__global__ __launch_bounds__(1024) void k_loss_final(const float* __restrict__ partials,
                                                     const float* __restrict__ gate_s,
                                                     float* __restrict__ out) {
    __shared__ float sh[16];
    int t = threadIdx.x;
    float s = 0.f;
#pragma unroll
    for (int i = 0; i < 4; i++) {
        float4 v = *(const float4*)(partials + t * 16 + i * 4);
        s += v.x + v.y + v.z + v.w;
    }
#pragma unroll
    for (int o = 32; o > 0; o >>= 1) s += __shfl_xor(s, o);
    int lane = t & 63, wv = t >> 6;
    if (lane == 0) sh[wv] = s;
    __syncthreads();
    if (t == 0) {
        float tot = 0.f;
#pragma unroll
        for (int i = 0; i < 16; i++) tot += sh[i];
        out[1048576] = tot * (1.0f / 67108864.0f);
        out[1048577] = *gate_s;
    }
}

extern "C" void kernel_launch(void* const* d_in, const int* in_sizes, int n_in,
                              void* d_out, int out_size, void* d_ws, size_t ws_size,
                              hipStream_t stream) {
    const float* seg = (const float*)d_in[0];
    const float* se  = (const float*)d_in[1];
    const float* Wq  = (const float*)d_in[2];
    const float* Wk  = (const float*)d_in[3];
    const float* Wv  = (const float*)d_in[4];
    const float* Wo  = (const float*)d_in[5];
    const float* Wrq = (const float*)d_in[6];
    const float* Wro = (const float*)d_in[7];
    const float* gb  = (const float*)d_in[8];
    const float* snw = (const float*)d_in[9];
    const float* snb = (const float*)d_in[10];
    const float* rnw = (const float*)d_in[11];
    const float* rnb = (const float*)d_in[12];
    float* out = (float*)d_out;

    char* ws = (char*)d_ws;
    size_t off = 0;
    auto alloc = [&](size_t bytes) -> char* {
        char* p = ws + off;
        off += (bytes + 1023) & ~(size_t)1023;
        return p;
    };

    unsigned short* Xb    = (unsigned short*)alloc((size_t)16384 * 4096 * 2);  // later aliased: rout_pre
    unsigned short* KVQ   = (unsigned short*)alloc((size_t)16384 * 768 * 2);
    unsigned short* Wt    = (unsigned short*)alloc((size_t)1024 * 4096 * 2);   // K|V|RQ|Q slabs
    unsigned short* Wot   = (unsigned short*)alloc((size_t)4096 * 256 * 2);
    unsigned short* Wrot  = (unsigned short*)alloc((size_t)4096 * 256 * 2);
    unsigned short* seb   = (unsigned short*)alloc((size_t)64 * 4096 * 2);
    float*          qf    = (float*)alloc((size_t)64 * 256 * 4);
    unsigned short* qb    = (unsigned short*)alloc((size_t)64 * 256 * 2);
    float*          L1    = (float*)alloc((size_t)4 * 64 * 4096 * 4);          // later aliased: L2
    unsigned short* attn  = (unsigned short*)alloc((size_t)4 * 64 * 4096 * 2);
    unsigned short* Vt    = (unsigned short*)alloc((size_t)4 * 256 * 4096 * 2); // later aliased: rmid
    float*          out1f = (float*)alloc((size_t)4 * 64 * 256 * 4);
    unsigned short* out1b = (unsigned short*)alloc((size_t)4 * 64 * 256 * 2);
    float*          out2  = (float*)alloc((size_t)256 * 4096 * 4);
    unsigned short* usb   = (unsigned short*)alloc((size_t)256 * 4096 * 2);
    float*          rkvf  = (float*)alloc((size_t)256 * 512 * 4);
    unsigned short* rkvb  = (unsigned short*)alloc((size_t)256 * 512 * 2);
    unsigned short* rvt   = (unsigned short*)alloc((size_t)4 * 256 * 64 * 2);
    unsigned short* rattn = (unsigned short*)alloc((size_t)4 * 4096 * 64 * 2);
    float*          gate_s = (float*)alloc(64);
    float*          partials = (float*)alloc((size_t)16384 * 4);
    unsigned short* routp = Xb;   // alias: Xb dead after proj GEMM
    float*          L2    = L1;   // alias: L1 dead after softmax_T
    unsigned short* rmid  = Vt;   // alias: Vt dead after attn@V

    hipMemsetAsync(out1f, 0, (size_t)4 * 64 * 256 * 4, stream);
    hipMemsetAsync(rkvf, 0, (size_t)256 * 512 * 4, stream);
    hipMemsetAsync(qf, 0, (size_t)64 * 256 * 4, stream);

    dim3 tb(32, 8);
    // weight transposes: Wk/Wv/Wrq/Wq [4096,256] -> Wt slabs; Wo,Wro [256,4096] -> [4096,256]
    k_transpose_f2b<<<dim3(8, 128, 1), tb, 0, stream>>>(Wk, 256, 0, Wt, 4096, 0);
    k_transpose_f2b<<<dim3(8, 128, 1), tb, 0, stream>>>(Wv, 256, 0, Wt + (size_t)256 * 4096, 4096, 0);
    k_transpose_f2b<<<dim3(8, 128, 1), tb, 0, stream>>>(Wrq, 256, 0, Wt + (size_t)512 * 4096, 4096, 0);
    k_transpose_f2b<<<dim3(8, 128, 1), tb, 0, stream>>>(Wq, 256, 0, Wt + (size_t)768 * 4096, 4096, 0);
    k_transpose_f2b<<<dim3(128, 8, 1), tb, 0, stream>>>(Wo, 4096, 0, Wot, 256, 0);
    k_transpose_f2b<<<dim3(128, 8, 1), tb, 0, stream>>>(Wro, 4096, 0, Wrot, 256, 0);

    // conversions
    k_cvt_bf16<<<4096, 256, 0, stream>>>(seg, Xb, (long)67108864);
    k_cvt_bf16<<<256, 256, 0, stream>>>(se, seb, (long)262144);
    k_gate<<<1, 64, 0, stream>>>(gb, gate_s);

    // q = se @ Wq : [64,4096] @ [4096,256], split-K=16, atomic f32 -> bf16
    k_gemm<64, 128, 1, 4, 2, 0><<<dim3(1, 2, 16), 256, 0, stream>>>(
        seb, 4096, 0, Wt + (size_t)768 * 4096, 4096, 0, qf, 256, 0, 4096, 16, 1.0f);
    k_cvt_bf16<<<16, 256, 0, stream>>>(qf, qb, (long)16384);

    // proj: [16384,4096] @ [4096,768] -> KVQ (cols: K|V|RQ), bf16 out
    k_gemm<128, 128, 2, 2, 1, 1><<<dim3(128, 6, 1), 256, 0, stream>>>(
        Xb, 4096, 0, Wt, 4096, 0, KVQ, 768, 0, 4096, 1, 1.0f);

    // L1 logits: per batch [64,256] @ [4096,256]^T * SCALE -> f32 [64][4096]
    k_gemm<64, 128, 1, 4, 0, 0><<<dim3(1, 32, 4), 256, 0, stream>>>(
        qb, 256, 0, KVQ, 768, 4096LL * 768, L1, 4096, 64LL * 4096, 256, 1, 0.0625f);
    k_softmax_T<<<256, 256, 0, stream>>>(L1, attn);

    // V^T per batch: [4096,256] (ld 768, col off 256) -> [256,4096]
    k_transpose_b2b<<<dim3(4, 64, 4), 256, 0, stream>>>(KVQ + 256, 768, 4096LL * 768, Vt, 4096, 256LL * 4096);

    // attn@V: per batch [64,4096] @ [4096,256], split-K=16, atomic f32
    k_gemm<64, 128, 1, 4, 2, 0><<<dim3(1, 2, 64), 256, 0, stream>>>(
        attn, 4096, 64LL * 4096, Vt, 4096, 256LL * 4096, out1f, 256, 64LL * 256, 4096, 16, 1.0f);
    k_cvt_bf16<<<64, 256, 0, stream>>>(out1f, out1b, (long)65536);

    // out2 = out1 @ Wo : [256,256] @ [256,4096] -> f32
    k_gemm<64, 128, 1, 4, 0, 0><<<dim3(4, 32, 1), 256, 0, stream>>>(
        out1b, 256, 0, Wot, 256, 0, out2, 4096, 0, 256, 1, 1.0f);

    // updated_slots = LN(slots + out2) -> d_out rows + bf16 copy
    k_ln_slots<<<256, 256, 0, stream>>>(se, out2, snw, snb, out, usb);

    // rk|rv = us @ [Wk|Wv] : [256,4096] @ [4096,512], split-K=16, atomic f32
    k_gemm<64, 128, 1, 4, 2, 0><<<dim3(4, 4, 16), 256, 0, stream>>>(
        usb, 4096, 0, Wt, 4096, 0, rkvf, 512, 0, 4096, 16, 1.0f);
    k_cvt_bf16<<<128, 256, 0, stream>>>(rkvf, rkvb, (long)131072);

    // rv^T per batch: [64,256] (ld 512, col off 256) -> [256,64]
    k_transpose_b2b<<<dim3(4, 1, 4), 256, 0, stream>>>(rkvb + 256, 512, 64LL * 512, rvt, 64, 256LL * 64);

    // L2 logits: per batch RQ [4096,256] @ rk[64,256]^T * SCALE -> f32 [4096][64]
    k_gemm<128, 64, 4, 1, 0, 1><<<dim3(32, 1, 4), 256, 0, stream>>>(
        KVQ + 512, 768, 4096LL * 768, rkvb, 512, 64LL * 512, L2, 64, 4096LL * 64, 256, 1, 0.0625f);
    k_softmax_S<<<4096, 256, 0, stream>>>(L2, rattn);

    // rmid = rattn @ rv : per batch [4096,64] @ [64,256] -> bf16
    k_gemm<128, 64, 4, 1, 1, 1><<<dim3(32, 4, 4), 256, 0, stream>>>(
        rattn, 64, 4096LL * 64, rvt, 64, 256LL * 64, rmid, 256, 4096LL * 256, 64, 1, 1.0f);

    // rout_pre = rmid @ Wro : [16384,256] @ [256,4096] -> bf16 (aliased on Xb)
    k_gemm<128, 128, 2, 2, 1, 1><<<dim3(128, 32, 1), 256, 0, stream>>>(
        rmid, 256, 0, Wrot, 256, 0, routp, 4096, 0, 256, 1, 1.0f);

    // fused LN + gate + MSE vs segment -> partials, then final reduce
    k_ln_loss<<<16384, 256, 0, stream>>>(routp, seg, rnw, rnb, gate_s, partials);
    k_loss_final<<<1, 1024, 0, stream>>>(partials, gate_s, out);

    (void)in_sizes; (void)n_in; (void)out_size; (void)ws_size;
}